// Round 1
// 688.022 us; speedup vs baseline: 1.1371x; 1.1371x over previous
//
#include <hip/hip_runtime.h>

#define TOK  4096
#define INF  4096
#define OUTF 11008
#define NG   704512   // number of quant groups
#define QD   172      // OUTF / 64

typedef __bf16 bf16x8 __attribute__((ext_vector_type(8)));
typedef float  floatx4 __attribute__((ext_vector_type(4)));

// ---------------- async global -> LDS, 16B per lane ----------------
__device__ inline void glds16(const __bf16* g, __bf16* l) {
  __builtin_amdgcn_global_load_lds(
      (const __attribute__((address_space(1))) void*)g,
      (__attribute__((address_space(3))) void*)l,
      16, 0, 0);
}

// ---------------- x (fp32) -> bf16 ----------------
__global__ __launch_bounds__(256) void convert_x_kernel(
    const float* __restrict__ x, __bf16* __restrict__ Xb) {
  size_t i = ((size_t)blockIdx.x * 256 + threadIdx.x) * 8;
  float4 a = *(const float4*)(x + i);
  float4 b = *(const float4*)(x + i + 4);
  bf16x8 o;
  o[0] = (__bf16)a.x; o[1] = (__bf16)a.y; o[2] = (__bf16)a.z; o[3] = (__bf16)a.w;
  o[4] = (__bf16)b.x; o[5] = (__bf16)b.y; o[6] = (__bf16)b.z; o[7] = (__bf16)b.w;
  *(bf16x8*)(Xb + i) = o;
}

// ---------------- dequant W_q -> bf16 Wb[OUTF][INF] ----------------
__global__ __launch_bounds__(256) void dequant_w_kernel(
    const int* __restrict__ Wq, const float* __restrict__ sc,
    const float* __restrict__ zp, __bf16* __restrict__ Wb) {
  const int b = blockIdx.x;          // 0 .. 32*172-1
  const int r = b / QD;              // 0..31
  const int q = b - r * QD;
  const int*   wrow = Wq + (size_t)r * NG + (size_t)q * INF;
  const float* srow = sc + (size_t)q * INF;
  const float* zrow = zp + (size_t)q * INF;
  __bf16* hrow = Wb + (size_t)(r * QD + q) * INF;
  __bf16* lrow = Wb + (size_t)((r + 32) * QD + q) * INF;
#pragma unroll
  for (int it = 0; it < 2; ++it) {
    const int k = ((int)threadIdx.x + it * 256) * 8;
    int4   w0 = *(const int4*)(wrow + k);
    int4   w1 = *(const int4*)(wrow + k + 4);
    float4 s0 = *(const float4*)(srow + k);
    float4 s1 = *(const float4*)(srow + k + 4);
    float4 z0 = *(const float4*)(zrow + k);
    float4 z1 = *(const float4*)(zrow + k + 4);
    bf16x8 hi, lo;
    hi[0] = (__bf16)(((float)((w0.x >> 4) & 0xF) - z0.x) * s0.x);
    hi[1] = (__bf16)(((float)((w0.y >> 4) & 0xF) - z0.y) * s0.y);
    hi[2] = (__bf16)(((float)((w0.z >> 4) & 0xF) - z0.z) * s0.z);
    hi[3] = (__bf16)(((float)((w0.w >> 4) & 0xF) - z0.w) * s0.w);
    hi[4] = (__bf16)(((float)((w1.x >> 4) & 0xF) - z1.x) * s1.x);
    hi[5] = (__bf16)(((float)((w1.y >> 4) & 0xF) - z1.y) * s1.y);
    hi[6] = (__bf16)(((float)((w1.z >> 4) & 0xF) - z1.z) * s1.z);
    hi[7] = (__bf16)(((float)((w1.w >> 4) & 0xF) - z1.w) * s1.w);
    lo[0] = (__bf16)(((float)(w0.x & 0xF) - z0.x) * s0.x);
    lo[1] = (__bf16)(((float)(w0.y & 0xF) - z0.y) * s0.y);
    lo[2] = (__bf16)(((float)(w0.z & 0xF) - z0.z) * s0.z);
    lo[3] = (__bf16)(((float)(w0.w & 0xF) - z0.w) * s0.w);
    lo[4] = (__bf16)(((float)(w1.x & 0xF) - z1.x) * s1.x);
    lo[5] = (__bf16)(((float)(w1.y & 0xF) - z1.y) * s1.y);
    lo[6] = (__bf16)(((float)(w1.z & 0xF) - z1.z) * s1.z);
    lo[7] = (__bf16)(((float)(w1.w & 0xF) - z1.w) * s1.w);
    *(bf16x8*)(hrow + k) = hi;
    *(bf16x8*)(lrow + k) = lo;
  }
}

// ---------------- 256x256 bf16 GEMM, counted-vmcnt pipeline ----------------
// C[4096][11008] = Xb[4096][4096] * Wb[11008][4096]^T + bias
// 256x256 tile, BK=64, 8 waves (2M x 4N), per-wave 128x64 output, 16x16x32 MFMA.
// LDS 128 KiB: As[2][256][64], Bs[2][256][64], XOR chunk swizzle j^(row&7)
// (verified conflict-free in previous version).
// Pipeline: waves read ALL their frags of tile t to regs -> lgkm(0)+barrier
// retires buf -> issue tile t+2 loads into it -> 64 MFMA -> vmcnt(8) waits only
// tile t+1's loads (t+2's stay in flight) -> barrier. No vmcnt(0) drain in loop.

#define MM_QUARTER(A_, JX, MOFF)                                              \
    _Pragma("unroll") for (int mi = 0; mi < 4; ++mi)                          \
      afr[mi] = *(const bf16x8*)((A_) + aoff + ((mi + (MOFF)) << 10) + (JX)); \
    __builtin_amdgcn_s_setprio(1);                                            \
    _Pragma("unroll") for (int mi = 0; mi < 4; ++mi)                          \
      _Pragma("unroll") for (int ni = 0; ni < 4; ++ni)                        \
        acc[mi + (MOFF)][ni] = __builtin_amdgcn_mfma_f32_16x16x32_bf16(       \
            afr[mi], bfr[ni], acc[mi + (MOFF)][ni], 0, 0, 0);                 \
    __builtin_amdgcn_s_setprio(0);

#define KTILE_COMPUTE(BUF)                                                    \
  { const __bf16* A_ = &As[BUF][0];                                           \
    const __bf16* B_ = &Bs[BUF][0];                                           \
    bf16x8 afr[4], bfr[4];                                                    \
    _Pragma("unroll") for (int ni = 0; ni < 4; ++ni)                          \
      bfr[ni] = *(const bf16x8*)(B_ + boff + (ni << 10) + jx0);               \
    MM_QUARTER(A_, jx0, 0)                                                    \
    MM_QUARTER(A_, jx0, 4)                                                    \
    _Pragma("unroll") for (int ni = 0; ni < 4; ++ni)                          \
      bfr[ni] = *(const bf16x8*)(B_ + boff + (ni << 10) + jx1);               \
    MM_QUARTER(A_, jx1, 0)                                                    \
    MM_QUARTER(A_, jx1, 4)                                                    \
  }

#define KTILE_SYNC(BUF, DO_STAGE, KOFF2, VMC)                                 \
    asm volatile("s_waitcnt lgkmcnt(0)" ::: "memory");                        \
    __builtin_amdgcn_s_barrier();                                             \
    asm volatile("" ::: "memory");                                            \
    if (DO_STAGE) {                                                           \
      _Pragma("unroll") for (int r = 0; r < 4; ++r)                           \
        glds16(gA[r] + (KOFF2), (BUF) ? lA1[r] : lA0[r]);                     \
      _Pragma("unroll") for (int r = 0; r < 4; ++r)                           \
        glds16(gB[r] + (KOFF2), (BUF) ? lB1[r] : lB0[r]);                     \
    }                                                                         \
    if ((VMC) == 8) { asm volatile("s_waitcnt vmcnt(8)" ::: "memory"); }      \
    else            { asm volatile("s_waitcnt vmcnt(0)" ::: "memory"); }      \
    __builtin_amdgcn_s_barrier();                                             \
    asm volatile("" ::: "memory");

__global__ __launch_bounds__(512, 2) void gemm_bt(
    const __bf16* __restrict__ Xb, const __bf16* __restrict__ Wb,
    const float* __restrict__ bias, float* __restrict__ out) {
  __shared__ __align__(16) __bf16 As[2][256 * 64];
  __shared__ __align__(16) __bf16 Bs[2][256 * 64];

  const int tid  = threadIdx.x;
  const int wave = tid >> 6;
  const int lane = tid & 63;

  // XCD-aware swizzle: 688 workgroups = 8 * 86 (bijective). Each XCD gets 2
  // full M-rows of blocks (A-panel reuse x43 in its L2; B streams via L3).
  const int orig = blockIdx.x;
  const int swz  = (orig & 7) * 86 + (orig >> 3);
  const int bn   = swz % 43;
  const int bm   = swz / 43;
  const int m0   = bm << 8;
  const int n0   = bn << 8;

  const int wm = (wave >> 2) << 7;   // 0 or 128
  const int wn = (wave & 3) << 6;    // 0,64,128,192

  // staging: per tile 8 rounds of 512 chunks (16B). chunk c -> row=c>>3,
  // LDS slot jl=c&7 holds global chunk j=jl^(row&7) (swizzle at the source,
  // LDS dest stays linear: wave-uniform base + lane*16).
  const __bf16* gA[4]; const __bf16* gB[4];
  __bf16 *lA0[4], *lB0[4], *lA1[4], *lB1[4];
#pragma unroll
  for (int r = 0; r < 4; ++r) {
    const int c   = (r << 9) + tid;          // 0..2047
    const int row = c >> 3;                  // 0..255
    const int j   = (c & 7) ^ (row & 7);
    gA[r] = Xb + (size_t)(m0 + row) * INF + (j << 3);
    gB[r] = Wb + (size_t)(n0 + row) * INF + (j << 3);
    const int lbase = ((r << 9) + (wave << 6)) << 3;   // wave-uniform
    lA0[r] = &As[0][lbase]; lA1[r] = &As[1][lbase];
    lB0[r] = &Bs[0][lbase]; lB1[r] = &Bs[1][lbase];
  }

  // prologue: tile0 -> buf0, tile1 -> buf1; wait only tile0 (8 newest in flight)
#pragma unroll
  for (int r = 0; r < 4; ++r) glds16(gA[r], lA0[r]);
#pragma unroll
  for (int r = 0; r < 4; ++r) glds16(gB[r], lB0[r]);
#pragma unroll
  for (int r = 0; r < 4; ++r) glds16(gA[r] + 64, lA1[r]);
#pragma unroll
  for (int r = 0; r < 4; ++r) glds16(gB[r] + 64, lB1[r]);

  floatx4 acc[8][4];
  const floatx4 z4 = {0.f, 0.f, 0.f, 0.f};
#pragma unroll
  for (int mi = 0; mi < 8; ++mi)
#pragma unroll
    for (int ni = 0; ni < 4; ++ni) acc[mi][ni] = z4;

  const int fr   = lane & 15;
  const int quad = lane >> 4;
  // fragment read offsets (elems); row&7 == fr&7 since wm/wn/mi*16 are mult of 8
  const int jx0  = ((0 * 4 + quad) ^ (fr & 7)) << 3;
  const int jx1  = ((1 * 4 + quad) ^ (fr & 7)) << 3;
  const int aoff = (wm + fr) << 6;
  const int boff = (wn + fr) << 6;

  asm volatile("s_waitcnt vmcnt(8)" ::: "memory");
  __builtin_amdgcn_s_barrier();
  asm volatile("" ::: "memory");

  // 64 K-tiles. tiles 0..61: stage t+2, counted wait vmcnt(8).
  for (int t = 0; t < 62; t += 2) {
    KTILE_COMPUTE(0) KTILE_SYNC(0, 1, ((t + 2) << 6), 8)
    KTILE_COMPUTE(1) KTILE_SYNC(1, 1, ((t + 3) << 6), 8)
  }
  KTILE_COMPUTE(0) KTILE_SYNC(0, 0, 0, 0)   // t=62: drain tile63
  KTILE_COMPUTE(1)                          // t=63: last, no sync needed

  // epilogue: C/D layout col = lane&15 (n), row = quad*4 + reg (m)
#pragma unroll
  for (int ni = 0; ni < 4; ++ni) {
    const int n = n0 + wn + (ni << 4) + fr;
    const float bv = bias[n];
#pragma unroll
    for (int mi = 0; mi < 8; ++mi) {
      const int mb = m0 + wm + (mi << 4) + (quad << 2);
#pragma unroll
      for (int j = 0; j < 4; ++j) {
        out[(size_t)(mb + j) * OUTF + n] = acc[mi][ni][j] + bv;
      }
    }
  }
}

extern "C" void kernel_launch(void* const* d_in, const int* in_sizes, int n_in,
                              void* d_out, int out_size, void* d_ws, size_t ws_size,
                              hipStream_t stream) {
  const float* x  = (const float*)d_in[0];   // [4096,4096] fp32
  const int*   Wq = (const int*)d_in[1];     // [32,704512] int32 (one byte each)
  const float* sc = (const float*)d_in[2];   // [704512]
  const float* zp = (const float*)d_in[3];   // [704512]
  const float* bs = (const float*)d_in[4];   // [11008]
  float* out = (float*)d_out;                // [4096,11008] fp32

  __bf16* Xb = (__bf16*)d_ws;                       // 32 MiB
  __bf16* Wb = Xb + (size_t)TOK * INF;              // 86 MiB

  convert_x_kernel<<<dim3((TOK * INF) / (256 * 8)), dim3(256), 0, stream>>>(x, Xb);
  dequant_w_kernel<<<dim3(32 * QD), dim3(256), 0, stream>>>(Wq, sc, zp, Wb);
  gemm_bt<<<dim3(OUTF / 256 * (TOK / 256)), dim3(512), 0, stream>>>(Xb, Wb, bs, out);
}